// Round 1
// baseline (306.058 us; speedup 1.0000x reference)
//
#include <hip/hip_runtime.h>
#include <cmath>

#define T_TOKENS 16384   // B*S
#define DIM 2048
#define HH 64            // complexity hidden
#define NG 4             // groups
#define EPG 16
#define NE 64            // experts
#define NJ 132           // 64 h + 4 group + 64 expert logits
#define JP 144           // padded J (16 j-tiles * 9)
#define BT 64            // tokens per block
#define DT 64            // d per tile
#define XS_STRIDE 65
#define WS_STRIDE 65
#define OT_STRIDE 133

__global__ void moe_zero(float* ws) {
    ws[threadIdx.x] = 0.f;   // 128 floats: [0..63]=usage sums, [64..127]=router-prob sums
}

__global__ __launch_bounds__(256, 2) void moe_main(
    const float* __restrict__ x, const float* __restrict__ Wg,
    const float* __restrict__ We, const float* __restrict__ W1,
    const float* __restrict__ b1, const float* __restrict__ W2,
    const float* __restrict__ b2, const int* __restrict__ minE,
    const int* __restrict__ maxE, float* __restrict__ out,
    float* __restrict__ ws_sums)
{
    __shared__ float xs[BT * XS_STRIDE];   // 16.6 KB
    __shared__ float wb[JP * WS_STRIDE];   // 37.4 KB, reused as out_tile [BT][OT_STRIDE]
    __shared__ float rp_s[BT * 17];
    __shared__ float sc_n1[BT], sc_n2[BT], sc_u2[BT];
    __shared__ int   sc_e1[BT], sc_e2[BT], sc_g[BT];
    __shared__ float s_usage[NE], s_rp[NE];

    const int tid = threadIdx.x;
    const int tokBase = blockIdx.x * BT;
    if (tid < NE) { s_usage[tid] = 0.f; s_rp[tid] = 0.f; }

    const int lane_d = tid & 63;
    const int row4   = tid >> 6;   // 0..3
    const int tx     = tid & 15;   // token tile (4 tokens)
    const int jy     = tid >> 4;   // 0..15 (9 outputs)

    float acc[4][9];
    #pragma unroll
    for (int i = 0; i < 4; ++i)
        #pragma unroll
        for (int q = 0; q < 9; ++q) acc[i][q] = 0.f;

    for (int dt = 0; dt < DIM / DT; ++dt) {
        const int d0 = dt * DT;
        // stage x tile [BT][DT], coalesced along d
        #pragma unroll
        for (int p = 0; p < BT / 4; ++p) {
            int t = row4 + p * 4;
            xs[t * XS_STRIDE + lane_d] = x[(size_t)(tokBase + t) * DIM + d0 + lane_d];
        }
        // stage weight tile [JP][DT]; rows >= NJ zero-filled
        #pragma unroll
        for (int p = 0; p < JP / 4; ++p) {
            int j = row4 + p * 4;
            float v = 0.f;
            int d = d0 + lane_d;
            if (j < HH)            v = W1[(size_t)j * DIM + d];
            else if (j < HH + NG)  v = Wg[(size_t)(j - HH) * DIM + d];
            else if (j < NJ)       v = We[(size_t)(j - HH - NG) * DIM + d];
            wb[j * WS_STRIDE + lane_d] = v;
        }
        __syncthreads();

        #pragma unroll 8
        for (int d = 0; d < DT; ++d) {
            float xv[4], wv[9];
            #pragma unroll
            for (int i = 0; i < 4; ++i) xv[i] = xs[(tx * 4 + i) * XS_STRIDE + d];
            #pragma unroll
            for (int q = 0; q < 9; ++q) wv[q] = wb[(jy * 9 + q) * WS_STRIDE + d];
            #pragma unroll
            for (int i = 0; i < 4; ++i)
                #pragma unroll
                for (int q = 0; q < 9; ++q)
                    acc[i][q] = fmaf(xv[i], wv[q], acc[i][q]);
        }
        __syncthreads();
    }

    // dump accumulators into LDS out_tile (reuse wb)
    float* ot = wb;
    #pragma unroll
    for (int i = 0; i < 4; ++i)
        #pragma unroll
        for (int q = 0; q < 9; ++q) {
            int j = jy * 9 + q;
            if (j < NJ) ot[(tx * 4 + i) * OT_STRIDE + j] = acc[i][q];
        }
    __syncthreads();

    // per-token scalar epilogue: one lane per token
    if (tid < BT) {
        const int t = tid;
        const float* o = &ot[t * OT_STRIDE];

        // complexity estimator
        float z = b2[0];
        #pragma unroll 8
        for (int i = 0; i < HH; ++i) {
            float h = o[i] + b1[i];
            h = h > 0.f ? h : 0.f;
            z = fmaf(W2[i], h, z);
        }
        float c = 1.f / (1.f + expf(-z));
        int mx = maxE[0], mn = minE[0];
        int k = (int)(c * (float)mx);          // trunc, matches .int() for >=0
        k = k < mn ? mn : k; k = k > mx ? mx : k;
        float u2 = (k >= 2) ? 1.f : 0.f;

        // group softmax / argmax (first max wins, matches jnp.argmax)
        float gm = -INFINITY; int gidx = 0;
        float gl[NG];
        #pragma unroll
        for (int g = 0; g < NG; ++g) {
            gl[g] = o[HH + g];
            if (gl[g] > gm) { gm = gl[g]; gidx = g; }
        }
        float gsum = 0.f;
        #pragma unroll
        for (int g = 0; g < NG; ++g) gsum += expf(gl[g] - gm);
        float gp_max = 1.f / gsum;             // expf(gm-gm)=1

        // expert softmax over chosen group's 16 logits
        float el[EPG]; float em = -INFINITY;
        #pragma unroll
        for (int j = 0; j < EPG; ++j) {
            el[j] = o[HH + NG + gidx * EPG + j];
            em = fmaxf(em, el[j]);
        }
        float ep[EPG]; float es = 0.f;
        #pragma unroll
        for (int j = 0; j < EPG; ++j) { ep[j] = expf(el[j] - em); es += ep[j]; }
        float inv_es = 1.f / es;
        #pragma unroll
        for (int j = 0; j < EPG; ++j) ep[j] *= inv_es;

        // top-2 (lowest index wins ties, matches lax.top_k)
        float v1 = -1.f; int i1 = 0;
        #pragma unroll
        for (int j = 0; j < EPG; ++j) if (ep[j] > v1) { v1 = ep[j]; i1 = j; }
        float v2 = -1.f; int i2 = 0;
        #pragma unroll
        for (int j = 0; j < EPG; ++j) if (j != i1 && ep[j] > v2) { v2 = ep[j]; i2 = j; }

        float denom = v1 + v2 * u2;
        float n1 = v1 / denom, n2 = v2 * u2 / denom;
        sc_n1[t] = n1; sc_n2[t] = n2; sc_u2[t] = u2;
        sc_e1[t] = gidx * EPG + i1; sc_e2[t] = gidx * EPG + i2; sc_g[t] = gidx;
        #pragma unroll
        for (int j = 0; j < EPG; ++j) rp_s[t * 17 + j] = gp_max * ep[j];
    }
    __syncthreads();

    // coalesced scatter of the three [BT][NE] output rows + block-local expert sums
    float* outD = out;
    float* outC = out + (size_t)T_TOKENS * NE;
    float* outR = out + (size_t)2 * T_TOKENS * NE;
    for (int idx = tid; idx < BT * NE; idx += 256) {
        int t = idx >> 6, e = idx & 63;
        int e1 = sc_e1[t], e2 = sc_e2[t];
        float disp = (e == e1 ? 1.f : 0.f) + (e == e2 ? sc_u2[t] : 0.f);
        float comb = (e == e1 ? sc_n1[t] : 0.f) + (e == e2 ? sc_n2[t] : 0.f);
        float rpv  = ((e >> 4) == sc_g[t]) ? rp_s[t * 17 + (e & 15)] : 0.f;
        size_t o = (size_t)(tokBase + t) * NE + e;
        outD[o] = disp; outC[o] = comb; outR[o] = rpv;
        atomicAdd(&s_usage[e], disp);
        atomicAdd(&s_rp[e], rpv);
    }
    __syncthreads();
    if (tid < NE) {
        atomicAdd(&ws_sums[tid], s_usage[tid]);
        atomicAdd(&ws_sums[NE + tid], s_rp[tid]);
    }
}

__global__ void moe_finalize(const float* __restrict__ ws_sums, float* __restrict__ out) {
    int l = threadIdx.x;  // 64 threads
    float v = ws_sums[l] * ws_sums[NE + l];
    #pragma unroll
    for (int off = 32; off; off >>= 1) v += __shfl_down(v, off, 64);
    if (l == 0) {
        float N = (float)T_TOKENS;
        out[(size_t)3 * T_TOKENS * NE] = v * (float)NE / (N * N);
    }
}

extern "C" void kernel_launch(void* const* d_in, const int* in_sizes, int n_in,
                              void* d_out, int out_size, void* d_ws, size_t ws_size,
                              hipStream_t stream) {
    const float* x  = (const float*)d_in[0];
    const float* Wg = (const float*)d_in[1];
    const float* We = (const float*)d_in[2];
    const float* W1 = (const float*)d_in[3];
    const float* b1 = (const float*)d_in[4];
    const float* W2 = (const float*)d_in[5];
    const float* b2 = (const float*)d_in[6];
    const int* minE = (const int*)d_in[7];
    const int* maxE = (const int*)d_in[8];
    float* out = (float*)d_out;
    float* ws  = (float*)d_ws;

    moe_zero<<<1, 128, 0, stream>>>(ws);
    moe_main<<<T_TOKENS / BT, 256, 0, stream>>>(x, Wg, We, W1, b1, W2, b2,
                                                minE, maxE, out, ws);
    moe_finalize<<<1, 64, 0, stream>>>(ws, out);
}